// Round 2
// baseline (486.710 us; speedup 1.0000x reference)
//
#include <hip/hip_runtime.h>

// Instant-NGP hashgrid forward.
// One thread per (point, level): tid = p*16 + lvl.
//  - output stores: lane-contiguous float2 -> fully coalesced 512B/wave
//  - 8 corner gathers: random 8B loads into the L3-resident 64MB table
// SCALINGS hardcoded as floor(16 * growth^l), growth = 2^(8/15).
// l=15: exact value 4096.0; numpy's f64 exp/log/pow chain floors to 4095
// (R1 bench: 4096 gave absmax 1.8e-3 == wrong-cell signature; all other
// levels have >=0.026 margin from an integer boundary, verified by hand).

#define TSZ_MASK ((1u << 19) - 1u)

static __constant__ float C_SCALE[16] = {
    16.f,  23.f,  33.f,   48.f,   70.f,   101.f,  147.f,  212.f,
    307.f, 445.f, 645.f,  933.f,  1351.f, 1955.f, 2830.f, 4095.f
};

__global__ __launch_bounds__(256) void hashgrid_fwd(
    const float* __restrict__ in,      // [B,3] f32
    const float2* __restrict__ tab,    // [16*2^19] float2
    float2* __restrict__ out,          // [B,16] float2  (== [B,32] f32)
    int nthreads)
{
    const int gid = blockIdx.x * 256 + threadIdx.x;
    if (gid >= nthreads) return;
    const int p   = gid >> 4;
    const int lvl = gid & 15;

    // 16 consecutive lanes share p -> L1 broadcasts these
    const float x = in[p * 3 + 0];
    const float y = in[p * 3 + 1];
    const float z = in[p * 3 + 2];
    const float s = C_SCALE[lvl];

    const float sx = x * s, sy = y * s, sz = z * s;
    const float fxf = floorf(sx), fyf = floorf(sy), fzf = floorf(sz);
    const float ox = sx - fxf, oy = sy - fyf, oz = sz - fzf;

    // reference: c = int32(ceil), f = int32(floor), then viewed as uint32
    const unsigned fx = (unsigned)(int)fxf;
    const unsigned fy = (unsigned)(int)fyf;
    const unsigned fz = (unsigned)(int)fzf;
    const unsigned cx = (unsigned)(int)ceilf(sx);
    const unsigned cy = (unsigned)(int)ceilf(sy);
    const unsigned cz = (unsigned)(int)ceilf(sz);

    // hash: (x*1) ^ (y*2654435761) ^ (z*805459861), mask, + lvl*2^19
    const unsigned hyc = cy * 2654435761u;
    const unsigned hyf = fy * 2654435761u;
    const unsigned hzc = cz * 805459861u;
    const unsigned hzf = fz * 805459861u;
    const unsigned base = (unsigned)lvl << 19;

    const unsigned i0 = ((cx ^ hyc ^ hzc) & TSZ_MASK) + base;  // (c,c,c)
    const unsigned i1 = ((cx ^ hyf ^ hzc) & TSZ_MASK) + base;  // (c,f,c)
    const unsigned i2 = ((fx ^ hyf ^ hzc) & TSZ_MASK) + base;  // (f,f,c)
    const unsigned i3 = ((fx ^ hyc ^ hzc) & TSZ_MASK) + base;  // (f,c,c)
    const unsigned i4 = ((cx ^ hyc ^ hzf) & TSZ_MASK) + base;  // (c,c,f)
    const unsigned i5 = ((cx ^ hyf ^ hzf) & TSZ_MASK) + base;  // (c,f,f)
    const unsigned i6 = ((fx ^ hyf ^ hzf) & TSZ_MASK) + base;  // (f,f,f)
    const unsigned i7 = ((fx ^ hyc ^ hzf) & TSZ_MASK) + base;  // (f,c,f)

    // 8 independent dwordx2 gathers — compiler issues all before first wait
    const float2 f0 = tab[i0];
    const float2 f1 = tab[i1];
    const float2 f2 = tab[i2];
    const float2 f3 = tab[i3];
    const float2 f4 = tab[i4];
    const float2 f5 = tab[i5];
    const float2 f6 = tab[i6];
    const float2 f7 = tab[i7];

    const float rx = 1.f - ox, ry = 1.f - oy, rz = 1.f - oz;
    float2 e;
    e.x = ((f0.x * ox + f3.x * rx) * oy + (f1.x * ox + f2.x * rx) * ry) * oz
        + ((f4.x * ox + f7.x * rx) * oy + (f5.x * ox + f6.x * rx) * ry) * rz;
    e.y = ((f0.y * ox + f3.y * rx) * oy + (f1.y * ox + f2.y * rx) * ry) * oz
        + ((f4.y * ox + f7.y * rx) * oy + (f5.y * ox + f6.y * rx) * ry) * rz;

    out[(p << 4) + lvl] = e;   // coalesced: contiguous float2 across lanes
}

extern "C" void kernel_launch(void* const* d_in, const int* in_sizes, int n_in,
                              void* d_out, int out_size, void* d_ws, size_t ws_size,
                              hipStream_t stream)
{
    const float*  in  = (const float*)d_in[0];
    const float2* tab = (const float2*)d_in[1];
    float2* out = (float2*)d_out;

    const int n_points = in_sizes[0] / 3;     // 524288
    const int nthreads = n_points * 16;       // 8388608
    const int blocks   = (nthreads + 255) / 256;

    hipLaunchKernelGGL(hashgrid_fwd, dim3(blocks), dim3(256), 0, stream,
                       in, tab, out, nthreads);
}

// Round 3
// 298.197 us; speedup vs baseline: 1.6322x; 1.6322x over previous
//
#include <hip/hip_runtime.h>

// Instant-NGP hashgrid forward — phase-aligned per-level passes.
//
// R2 counters: monolithic kernel = 488us, FETCH_SIZE 1.76GB (table is 64MB!)
//  -> random gathers miss per-XCD L2 because every wave mixes all 16 levels.
// Fix: process ONE level at a time across the whole GPU. Each XCD's 4MB L2
// then holds exactly that level's 4MB table slice (replicated, read-only).
//  - levels 0-4 combined in one launch (hot-set ~3.3MB total)
//  - levels 5-15 one launch each (4MB slice each)
//  - gather kernels write LEVEL-MAJOR scratch (coalesced 8B stores);
//    point-major direct writes would be stride-128B partial-line RMW (~1GB).
//  - final LDS-tiled transpose: level-major scratch -> [B,16] float2 out.
// Non-temporal loads/stores for the streaming traffic keep L2 for the table.
// Fallback: monolithic R2 kernel (known-pass) if ws too small / B != 2^19.

typedef float f2 __attribute__((ext_vector_type(2)));
typedef float f4 __attribute__((ext_vector_type(4)));

#define TSZ_MASK  ((1u << 19) - 1u)
#define LOG2_B    19                 // B = 524288 points = 2^19 (checked)

static __constant__ float C_SCALE[16] = {
    16.f,  23.f,  33.f,   48.f,   70.f,   101.f,  147.f,  212.f,
    307.f, 445.f, 645.f,  933.f,  1351.f, 1955.f, 2830.f, 4095.f
};

// ---------------------------------------------------------------- gather ---
// One thread per (point, level-within-range). gid = (lvl-lvl0)*2^19 + p.
// Writes scratch[lvl*2^19 + p] (level-major, fully coalesced).
__global__ __launch_bounds__(256) void hashgrid_gather(
    const float* __restrict__ in,     // [B,3]
    const f2*    __restrict__ tab,    // [16*2^19]
    f2*          __restrict__ scratch,// [16*2^19] level-major
    int lvl0)
{
    const unsigned gid = blockIdx.x * 256 + threadIdx.x;
    const int lvl = lvl0 + (int)(gid >> LOG2_B);
    const unsigned p = gid & TSZ_MASK;

    const float x = __builtin_nontemporal_load(&in[p * 3 + 0]);
    const float y = __builtin_nontemporal_load(&in[p * 3 + 1]);
    const float z = __builtin_nontemporal_load(&in[p * 3 + 2]);
    const float s = C_SCALE[lvl];

    const float sx = x * s, sy = y * s, sz = z * s;
    const float fxf = floorf(sx), fyf = floorf(sy), fzf = floorf(sz);
    const float ox = sx - fxf, oy = sy - fyf, oz = sz - fzf;

    const unsigned fx = (unsigned)(int)fxf;
    const unsigned fy = (unsigned)(int)fyf;
    const unsigned fz = (unsigned)(int)fzf;
    const unsigned cx = (unsigned)(int)ceilf(sx);
    const unsigned cy = (unsigned)(int)ceilf(sy);
    const unsigned cz = (unsigned)(int)ceilf(sz);

    const unsigned hyc = cy * 2654435761u;
    const unsigned hyf = fy * 2654435761u;
    const unsigned hzc = cz * 805459861u;
    const unsigned hzf = fz * 805459861u;

    const f2* __restrict__ tl = tab + ((size_t)lvl << LOG2_B);

    const unsigned i0 = (cx ^ hyc ^ hzc) & TSZ_MASK;  // (c,c,c)
    const unsigned i1 = (cx ^ hyf ^ hzc) & TSZ_MASK;  // (c,f,c)
    const unsigned i2 = (fx ^ hyf ^ hzc) & TSZ_MASK;  // (f,f,c)
    const unsigned i3 = (fx ^ hyc ^ hzc) & TSZ_MASK;  // (f,c,c)
    const unsigned i4 = (cx ^ hyc ^ hzf) & TSZ_MASK;  // (c,c,f)
    const unsigned i5 = (cx ^ hyf ^ hzf) & TSZ_MASK;  // (c,f,f)
    const unsigned i6 = (fx ^ hyf ^ hzf) & TSZ_MASK;  // (f,f,f)
    const unsigned i7 = (fx ^ hyc ^ hzf) & TSZ_MASK;  // (f,c,f)

    const f2 f0 = tl[i0];
    const f2 f1 = tl[i1];
    const f2 f2_ = tl[i2];
    const f2 f3 = tl[i3];
    const f2 f4_ = tl[i4];
    const f2 f5 = tl[i5];
    const f2 f6 = tl[i6];
    const f2 f7 = tl[i7];

    const float rx = 1.f - ox, ry = 1.f - oy, rz = 1.f - oz;
    f2 e = ((f0 * ox + f3 * rx) * oy + (f1 * ox + f2_ * rx) * ry) * oz
         + ((f4_ * ox + f7 * rx) * oy + (f5 * ox + f6 * rx) * ry) * rz;

    __builtin_nontemporal_store(e, &scratch[((size_t)lvl << LOG2_B) + p]);
}

// ------------------------------------------------------------- transpose ---
// Level-major scratch -> point-major out, via LDS tile (64 points x 16 lvls).
__global__ __launch_bounds__(256) void hashgrid_transpose(
    const f2* __restrict__ scratch,   // [16][2^19] f2
    f4*       __restrict__ out)       // [B*8] f4 == [B,32] f32
{
    __shared__ f2 tile[64][17];       // +1 pad: phase1 4-way, phase2 ~2-way
    const int t = threadIdx.x;
    const int lane = t & 63, w = t >> 6;
    const unsigned pbase = blockIdx.x * 64;

#pragma unroll
    for (int i = 0; i < 4; ++i) {
        const int lvl = w * 4 + i;
        tile[lane][lvl] = __builtin_nontemporal_load(
            &scratch[((size_t)lvl << LOG2_B) + pbase + lane]);
    }
    __syncthreads();

    const unsigned obase = blockIdx.x * 512;  // 64 pts * 8 f4
#pragma unroll
    for (int rep = 0; rep < 2; ++rep) {
        const int j = t + rep * 256;
        const int pt = j >> 3, k = j & 7;
        const f2 a = tile[pt][2 * k];
        const f2 b = tile[pt][2 * k + 1];
        f4 v = {a.x, a.y, b.x, b.y};
        __builtin_nontemporal_store(v, &out[obase + j]);
    }
}

// ------------------------------------------------- monolithic fallback ----
__global__ __launch_bounds__(256) void hashgrid_mono(
    const float* __restrict__ in, const f2* __restrict__ tab,
    f2* __restrict__ out, int nthreads)
{
    const int gid = blockIdx.x * 256 + threadIdx.x;
    if (gid >= nthreads) return;
    const int p = gid >> 4;
    const int lvl = gid & 15;

    const float x = in[p * 3 + 0];
    const float y = in[p * 3 + 1];
    const float z = in[p * 3 + 2];
    const float s = C_SCALE[lvl];

    const float sx = x * s, sy = y * s, sz = z * s;
    const float fxf = floorf(sx), fyf = floorf(sy), fzf = floorf(sz);
    const float ox = sx - fxf, oy = sy - fyf, oz = sz - fzf;

    const unsigned fx = (unsigned)(int)fxf, fy = (unsigned)(int)fyf,
                   fz = (unsigned)(int)fzf;
    const unsigned cx = (unsigned)(int)ceilf(sx), cy = (unsigned)(int)ceilf(sy),
                   cz = (unsigned)(int)ceilf(sz);

    const unsigned hyc = cy * 2654435761u, hyf = fy * 2654435761u;
    const unsigned hzc = cz * 805459861u,  hzf = fz * 805459861u;
    const unsigned base = (unsigned)lvl << 19;

    const unsigned i0 = ((cx ^ hyc ^ hzc) & TSZ_MASK) + base;
    const unsigned i1 = ((cx ^ hyf ^ hzc) & TSZ_MASK) + base;
    const unsigned i2 = ((fx ^ hyf ^ hzc) & TSZ_MASK) + base;
    const unsigned i3 = ((fx ^ hyc ^ hzc) & TSZ_MASK) + base;
    const unsigned i4 = ((cx ^ hyc ^ hzf) & TSZ_MASK) + base;
    const unsigned i5 = ((cx ^ hyf ^ hzf) & TSZ_MASK) + base;
    const unsigned i6 = ((fx ^ hyf ^ hzf) & TSZ_MASK) + base;
    const unsigned i7 = ((fx ^ hyc ^ hzf) & TSZ_MASK) + base;

    const f2 f0 = tab[i0], f1 = tab[i1], f2_ = tab[i2], f3 = tab[i3];
    const f2 f4_ = tab[i4], f5 = tab[i5], f6 = tab[i6], f7 = tab[i7];

    const float rx = 1.f - ox, ry = 1.f - oy, rz = 1.f - oz;
    f2 e = ((f0 * ox + f3 * rx) * oy + (f1 * ox + f2_ * rx) * ry) * oz
         + ((f4_ * ox + f7 * rx) * oy + (f5 * ox + f6 * rx) * ry) * rz;

    out[(p << 4) + lvl] = e;
}

// ------------------------------------------------------------------ entry --
extern "C" void kernel_launch(void* const* d_in, const int* in_sizes, int n_in,
                              void* d_out, int out_size, void* d_ws, size_t ws_size,
                              hipStream_t stream)
{
    const float* in  = (const float*)d_in[0];
    const f2*    tab = (const f2*)d_in[1];

    const int n_points = in_sizes[0] / 3;
    const size_t scratch_bytes = (size_t)16 * (1u << LOG2_B) * sizeof(f2); // 64MB

    if (n_points == (1 << LOG2_B) && ws_size >= scratch_bytes) {
        f2* scratch = (f2*)d_ws;
        // levels 0-4 combined: hot set ~3.3MB, fits one L2 alongside streams
        hipLaunchKernelGGL(hashgrid_gather, dim3((5u << LOG2_B) / 256), dim3(256),
                           0, stream, in, tab, scratch, 0);
        // levels 5-15: one 4MB table slice per launch -> L2-resident per XCD
        for (int l = 5; l < 16; ++l) {
            hipLaunchKernelGGL(hashgrid_gather, dim3((1u << LOG2_B) / 256), dim3(256),
                               0, stream, in, tab, scratch, l);
        }
        hipLaunchKernelGGL(hashgrid_transpose, dim3((1u << LOG2_B) / 64), dim3(256),
                           0, stream, scratch, (f4*)d_out);
    } else {
        const int nthreads = n_points * 16;
        hipLaunchKernelGGL(hashgrid_mono, dim3((nthreads + 255) / 256), dim3(256),
                           0, stream, in, tab, (f2*)d_out, nthreads);
    }
}

// Round 4
// 286.283 us; speedup vs baseline: 1.7001x; 1.0416x over previous
//
#include <hip/hip_runtime.h>

// Instant-NGP hashgrid forward — single-launch, level-major-ordered gather.
//
// R3: per-level launches fixed L2 thrash (488->298us) but ran at 0.36
// gathers/cyc/CU vs 0.53 for the bigger combined launch: 32-waves/CU
// launches are latency-bound + inter-launch bubbles. Binding resource is
// L2->L1 line traffic (~64B per random 8B gather), NOT HBM (4-8% peak).
//
// R4: ONE gather launch, blocks ordered level-major (lvl = blockIdx>>11).
// HW dispatches blocks ~in ID order and <=2048 blocks are in flight
// (256CU x 8 blocks @ 256thr) = exactly one level's block count, so the
// active L2 footprint stays ~one 4MB level slice while the scheduler sees
// the whole 8.4M-thread grid (no bubbles, full TLP). Each thread handles
// 2 points (16 outstanding gathers) for latency-hiding MLP.
// Scratch stays level-major (coalesced stores); LDS transpose to [B,16].

typedef float f2 __attribute__((ext_vector_type(2)));
typedef float f4 __attribute__((ext_vector_type(4)));

#define TSZ_MASK  ((1u << 19) - 1u)
#define LOG2_B    19                 // B = 524288 points = 2^19

static __constant__ float C_SCALE[16] = {
    16.f,  23.f,  33.f,   48.f,   70.f,   101.f,  147.f,  212.f,
    307.f, 445.f, 645.f,  933.f,  1351.f, 1955.f, 2830.f, 4095.f
};

// ---------------------------------------------------------------- gather ---
// Grid: 16 levels x 1024 blocks x 256 threads x 2 points.
// Block b: lvl = b >> 10, chunk = b & 1023; points p0 = chunk*512 + tid,
// p1 = p0 + 256.  (1024 blocks/level keeps dispatch window ~2 levels max.)
struct Corner8 { unsigned i[8]; float ox, oy, oz; };

__device__ __forceinline__ Corner8 corner_idx(const float* __restrict__ in,
                                              unsigned p, float s)
{
    const float x = __builtin_nontemporal_load(&in[p * 3 + 0]);
    const float y = __builtin_nontemporal_load(&in[p * 3 + 1]);
    const float z = __builtin_nontemporal_load(&in[p * 3 + 2]);

    const float sx = x * s, sy = y * s, sz = z * s;
    const float fxf = floorf(sx), fyf = floorf(sy), fzf = floorf(sz);

    Corner8 r;
    r.ox = sx - fxf; r.oy = sy - fyf; r.oz = sz - fzf;

    const unsigned fx = (unsigned)(int)fxf;
    const unsigned fy = (unsigned)(int)fyf;
    const unsigned fz = (unsigned)(int)fzf;
    const unsigned cx = (unsigned)(int)ceilf(sx);
    const unsigned cy = (unsigned)(int)ceilf(sy);
    const unsigned cz = (unsigned)(int)ceilf(sz);

    const unsigned hyc = cy * 2654435761u;
    const unsigned hyf = fy * 2654435761u;
    const unsigned hzc = cz * 805459861u;
    const unsigned hzf = fz * 805459861u;

    r.i[0] = (cx ^ hyc ^ hzc) & TSZ_MASK;  // (c,c,c)
    r.i[1] = (cx ^ hyf ^ hzc) & TSZ_MASK;  // (c,f,c)
    r.i[2] = (fx ^ hyf ^ hzc) & TSZ_MASK;  // (f,f,c)
    r.i[3] = (fx ^ hyc ^ hzc) & TSZ_MASK;  // (f,c,c)
    r.i[4] = (cx ^ hyc ^ hzf) & TSZ_MASK;  // (c,c,f)
    r.i[5] = (cx ^ hyf ^ hzf) & TSZ_MASK;  // (c,f,f)
    r.i[6] = (fx ^ hyf ^ hzf) & TSZ_MASK;  // (f,f,f)
    r.i[7] = (fx ^ hyc ^ hzf) & TSZ_MASK;  // (f,c,f)
    return r;
}

__device__ __forceinline__ f2 trilerp(const f2* __restrict__ tl, const Corner8& c)
{
    const f2 f0 = tl[c.i[0]], f1 = tl[c.i[1]], f2_ = tl[c.i[2]], f3 = tl[c.i[3]];
    const f2 f4_ = tl[c.i[4]], f5 = tl[c.i[5]], f6 = tl[c.i[6]], f7 = tl[c.i[7]];
    const float rx = 1.f - c.ox, ry = 1.f - c.oy, rz = 1.f - c.oz;
    return ((f0 * c.ox + f3 * rx) * c.oy + (f1 * c.ox + f2_ * rx) * ry) * c.oz
         + ((f4_ * c.ox + f7 * rx) * c.oy + (f5 * c.ox + f6 * rx) * ry) * rz;
}

__global__ __launch_bounds__(256) void hashgrid_gather(
    const float* __restrict__ in,     // [B,3]
    const f2*    __restrict__ tab,    // [16*2^19]
    f2*          __restrict__ scratch)// [16][2^19] level-major
{
    const unsigned b = blockIdx.x;
    const int lvl = (int)(b >> 10);
    const unsigned p0 = (b & 1023u) * 512u + threadIdx.x;
    const unsigned p1 = p0 + 256u;
    const float s = C_SCALE[lvl];
    const f2* __restrict__ tl = tab + ((size_t)lvl << LOG2_B);

    // compute both index sets, then both gather sets are in flight together
    const Corner8 ca = corner_idx(in, p0, s);
    const Corner8 cb = corner_idx(in, p1, s);
    const f2 ea = trilerp(tl, ca);
    const f2 eb = trilerp(tl, cb);

    f2* __restrict__ sl = scratch + ((size_t)lvl << LOG2_B);
    __builtin_nontemporal_store(ea, &sl[p0]);
    __builtin_nontemporal_store(eb, &sl[p1]);
}

// ------------------------------------------------------------- transpose ---
// Level-major scratch -> point-major out, via LDS tile (64 points x 16 lvls).
__global__ __launch_bounds__(256) void hashgrid_transpose(
    const f2* __restrict__ scratch,   // [16][2^19] f2
    f4*       __restrict__ out)       // [B*8] f4 == [B,32] f32
{
    __shared__ f2 tile[64][17];
    const int t = threadIdx.x;
    const int lane = t & 63, w = t >> 6;
    const unsigned pbase = blockIdx.x * 64;

#pragma unroll
    for (int i = 0; i < 4; ++i) {
        const int lvl = w * 4 + i;
        tile[lane][lvl] = __builtin_nontemporal_load(
            &scratch[((size_t)lvl << LOG2_B) + pbase + lane]);
    }
    __syncthreads();

    const unsigned obase = blockIdx.x * 512;  // 64 pts * 8 f4
#pragma unroll
    for (int rep = 0; rep < 2; ++rep) {
        const int j = t + rep * 256;
        const int pt = j >> 3, k = j & 7;
        const f2 a = tile[pt][2 * k];
        const f2 b = tile[pt][2 * k + 1];
        f4 v = {a.x, a.y, b.x, b.y};
        __builtin_nontemporal_store(v, &out[obase + j]);
    }
}

// ------------------------------------------------- monolithic fallback ----
__global__ __launch_bounds__(256) void hashgrid_mono(
    const float* __restrict__ in, const f2* __restrict__ tab,
    f2* __restrict__ out, int nthreads)
{
    const int gid = blockIdx.x * 256 + threadIdx.x;
    if (gid >= nthreads) return;
    const int p = gid >> 4;
    const int lvl = gid & 15;
    const float s = C_SCALE[lvl];
    const Corner8 c = corner_idx(in, p, s);
    const f2* __restrict__ tl = tab + ((size_t)lvl << LOG2_B);
    out[(p << 4) + lvl] = trilerp(tl, c);
}

// ------------------------------------------------------------------ entry --
extern "C" void kernel_launch(void* const* d_in, const int* in_sizes, int n_in,
                              void* d_out, int out_size, void* d_ws, size_t ws_size,
                              hipStream_t stream)
{
    const float* in  = (const float*)d_in[0];
    const f2*    tab = (const f2*)d_in[1];

    const int n_points = in_sizes[0] / 3;
    const size_t scratch_bytes = (size_t)16 * (1u << LOG2_B) * sizeof(f2); // 64MB

    if (n_points == (1 << LOG2_B) && ws_size >= scratch_bytes) {
        f2* scratch = (f2*)d_ws;
        // 16 levels x 1024 blocks x 256 thr x 2 pts; level-major block order
        hipLaunchKernelGGL(hashgrid_gather, dim3(16 * 1024), dim3(256),
                           0, stream, in, tab, scratch);
        hipLaunchKernelGGL(hashgrid_transpose, dim3((1u << LOG2_B) / 64), dim3(256),
                           0, stream, scratch, (f4*)d_out);
    } else {
        const int nthreads = n_points * 16;
        hipLaunchKernelGGL(hashgrid_mono, dim3((nthreads + 255) / 256), dim3(256),
                           0, stream, in, tab, (f2*)d_out, nthreads);
    }
}